// Round 9
// baseline (920.477 us; speedup 1.0000x reference)
//
#include <hip/hip_runtime.h>
#include <hip/hip_bf16.h>
#include <stdint.h>

#define NB 512
#define NW 40
#define NE 512
#define NH 512
#define NV 12000
#define G4 2048

typedef unsigned short u16;
typedef unsigned int u32;
typedef unsigned long long u64;
typedef __attribute__((ext_vector_type(8))) short short8;
typedef __attribute__((ext_vector_type(4))) float f32x4;

__device__ __forceinline__ unsigned short f2bf(float f) {
  unsigned int u = __float_as_uint(f);
  u += 0x7FFF + ((u >> 16) & 1);
  return (unsigned short)(u >> 16);
}
__device__ __forceinline__ float bf2f(unsigned short b) {
  return __uint_as_float(((unsigned int)b) << 16);
}
__device__ __forceinline__ float loadIn(const void* p, long i, int bf) {
  return bf ? bf2f(((const u16*)p)[i]) : ((const float*)p)[i];
}
// exp-based tanh: |err| ~1e-7 abs, saturates cleanly (exp->inf => 1).
__device__ __forceinline__ float fast_tanh(float x) {
  float ax = __builtin_fabsf(x);
  float t = 1.f - 2.f * __builtin_amdgcn_rcpf(__expf(ax + ax) + 1.f);
  return __builtin_copysignf(t, x);
}
__device__ __forceinline__ float sigm(float x) {
  return __builtin_amdgcn_rcpf(1.f + __expf(-x));
}

// ---------------- dtype detector ----------------
__global__ void detect_kernel(const u16* p, int* flag) {
  __shared__ int cnt;
  int i = threadIdx.x;
  if (i == 0) cnt = 0;
  __syncthreads();
  unsigned short u = p[2 * (i * 1001)];
  int e = (u >> 7) & 0xFF;
  if (e >= 100 && e <= 126) atomicAdd(&cnt, 1);
  __syncthreads();
  if (i == 0) *flag = (cnt >= 32) ? 1 : 0;
}

// ---------------- tableT = bf16(tanh(lookup_W^T)), (V, E) ----------------
__global__ void table_kernel(const void* lookup, const int* flag, u16* tableT) {
  __shared__ float tile[64][65];
  int bf = *flag;
  int v0 = blockIdx.x * 64, e0 = blockIdx.y * 64;
  int tx = threadIdx.x, ty = threadIdx.y;  // (64,4)
#pragma unroll
  for (int r = 0; r < 16; ++r) {
    int e = r * 4 + ty, v = tx;
    if (v0 + v < NV)
      tile[e][v] = tanhf(loadIn(lookup, (long)(e0 + e) * NV + v0 + v, bf));
  }
  __syncthreads();
#pragma unroll
  for (int r = 0; r < 16; ++r) {
    int v = r * 4 + ty, e = tx;
    if (v0 + v < NV)
      tableT[(long)(v0 + v) * NE + e0 + e] = f2bf(tile[e][v]);
  }
}

// ---------------- pack weights: Wc[d] rows = [wih | whh], bf16 ------------
// Also writes G[0] = bias row (layer0) and zeroes the 512-slot bar region
// (layer0 uses bar[0..255], layer1 bar[256..511] -- no zero_bar dispatches).
__global__ void pack_kernel(const void* wih0, const void* whh0, const void* b0,
                            const void* wih1, const void* whh1, const void* b1,
                            const int* flag, u16* Wc0, u16* Wc1, float* bsum,
                            u16* G, unsigned int* bar) {
  const long N0 = 2L * G4 * 1024, N1 = 2L * G4 * 1536;
  const long NB2 = 2L * 2 * G4;
  long idx = (long)blockIdx.x * 256 + threadIdx.x;
  int bf = *flag;
  if (idx < N0) {
    int d = (int)(idx / (G4 * 1024));
    int rem = (int)(idx % (long)(G4 * 1024));
    int g = rem / 1024, k = rem % 1024;
    float v = (k < 512) ? loadIn(wih0, ((long)d * G4 + g) * 512 + k, bf)
                        : loadIn(whh0, ((long)d * G4 + g) * 512 + (k - 512), bf);
    Wc0[idx] = f2bf(v);
  } else if (idx < N0 + N1) {
    long i2 = idx - N0;
    int d = (int)(i2 / (G4 * 1536));
    int rem = (int)(i2 % (long)(G4 * 1536));
    int g = rem / 1536, k = rem % 1536;
    float v = (k < 1024) ? loadIn(wih1, ((long)d * G4 + g) * 1024 + k, bf)
                         : loadIn(whh1, ((long)d * G4 + g) * 512 + (k - 1024), bf);
    Wc1[i2] = f2bf(v);
  } else if (idx < N0 + N1 + NB2) {
    long i3 = idx - N0 - N1;  // [layer][d][g]
    int layer = (int)(i3 / (2 * G4));
    int d = (int)((i3 / G4) & 1);
    int g = (int)(i3 % G4);
    const void* bb = layer ? b1 : b0;
    float v = loadIn(bb, (long)d * 2 * G4 + g, bf) +
              loadIn(bb, (long)d * 2 * G4 + G4 + g, bf);
    bsum[i3] = v;
  } else if (idx < N0 + N1 + NB2 + 4096) {
    int n = (int)(idx - N0 - N1 - NB2);  // [0,4096): G[0] bias row
    int d = n >> 11, loc = n & 2047;
    int colb = loc >> 7, rr = loc & 127;
    int jn = rr >> 2, g = rr & 3;
    int grow = g * 512 + colb * 32 + jn;
    float v = loadIn(b0, (long)d * 2 * G4 + grow, bf) +
              loadIn(b0, (long)d * 2 * G4 + G4 + grow, bf);
    G[n] = f2bf(v);
  } else if (idx < N0 + N1 + NB2 + 4096 + 512) {
    bar[(int)(idx - N0 - N1 - NB2 - 4096)] = 0u;
  }
}

// ---------------- G GEMM: G[1+v] = tableT[v] @ Wih0^T + bias --------------
// layer-0 x-gates depend on the token only through q (12001 distinct
// values) -- compute per-VOCAB-ROW gates once (50 GF) instead of per-token.
// G row layout: [d 2][colb 16][jn*4+g 128] (matches lstm xgv gather).
__global__ __launch_bounds__(256, 3) void g_gemm(
    const u16* __restrict__ tableT, const u16* __restrict__ Wc,
    const float* __restrict__ bsumL, u16* __restrict__ G) {
  __shared__ __align__(16) char lds[32768];  // A 16K + B 16K
  const int tid = threadIdx.x;
  const int lane = tid & 63, wv = tid >> 6;
  const int wm = wv & 1, wn = wv >> 1;
  const int col = lane & 15, quad = lane >> 4;
  const int bx = blockIdx.x >> 5;  // 0..93
  const int by = blockIdx.x & 31;
  const int tb0 = bx * 128;  // vocab row base
  const int d = by >> 4, colb = by & 15, j0 = colb * 32;

  f32x4 zero = {0.f, 0.f, 0.f, 0.f};
  f32x4 acc[4][4];
#pragma unroll
  for (int i = 0; i < 4; ++i)
#pragma unroll
    for (int j = 0; j < 4; ++j) acc[i][j] = zero;

  for (int it = 0; it < 8; ++it) {
    int k0 = it << 6;
#pragma unroll
    for (int p = 0; p < 8; ++p) {
      int c = p * 256 + tid;  // [0,2048)
      const u16* gsrc;
      if (c < 1024) {  // A rows (vocab)
        int r = c >> 3, sl = c & 7;
        int kk = k0 + ((sl * 8) ^ ((r & 7) << 3));
        gsrc = tableT + (long)(tb0 + r) * 512 + kk;
      } else {
        int cb = c - 1024;
        int r = cb >> 3, sl = cb & 7;
        int kk = k0 + ((sl * 8) ^ ((r & 7) << 3));
        int grow = (r >> 5) * 512 + j0 + (r & 31);
        gsrc = Wc + ((long)d * G4 + grow) * 1024 + kk;  // wih part (k<512)
      }
      __builtin_amdgcn_global_load_lds(
          (const __attribute__((address_space(1))) void*)(const void*)gsrc,
          (__attribute__((address_space(3))) void*)(lds + p * 4096 + wv * 1024),
          16, 0, 0);
    }
    __syncthreads();
    const u16* As = (const u16*)lds;
    const u16* Bs = (const u16*)(lds + 16384);
#pragma unroll
    for (int ks = 0; ks < 2; ++ks) {
      short8 afr[4], bfr[4];
#pragma unroll
      for (int mf = 0; mf < 4; ++mf) {
        int rm = wm * 64 + mf * 16 + col;
        int sl = (ks * 32 + quad * 8) ^ ((rm & 7) << 3);
        afr[mf] = *(const short8*)(As + rm * 64 + sl);
      }
#pragma unroll
      for (int nf = 0; nf < 4; ++nf) {
        int br = wn * 64 + nf * 16 + col;
        int sl = (ks * 32 + quad * 8) ^ ((br & 7) << 3);
        bfr[nf] = *(const short8*)(Bs + br * 64 + sl);
      }
#pragma unroll
      for (int mf = 0; mf < 4; ++mf)
#pragma unroll
        for (int nf = 0; nf < 4; ++nf)
          acc[mf][nf] = __builtin_amdgcn_mfma_f32_16x16x32_bf16(
              afr[mf], bfr[nf], acc[mf][nf], 0, 0, 0);
    }
    __syncthreads();
  }

  float bias[4];
#pragma unroll
  for (int nf = 0; nf < 4; ++nf) {
    int n = wn * 64 + nf * 16 + col;
    bias[nf] = bsumL[d * G4 + (n >> 5) * 512 + j0 + (n & 31)];
  }
#pragma unroll
  for (int mf = 0; mf < 4; ++mf)
#pragma unroll
    for (int nf = 0; nf < 4; ++nf) {
      int n = wn * 64 + nf * 16 + col;
      int g = n >> 5, jn = n & 31;
#pragma unroll
      for (int r = 0; r < 4; ++r) {
        int m = wm * 64 + mf * 16 + quad * 4 + r;
        int v = tb0 + m;
        if (v < NV)
          G[(long)(v + 1) * 4096 + ((d * 16 + colb) << 7) + jn * 4 + g] =
              f2bf(acc[mf][nf][r] + bias[nf]);
      }
    }
}

// ---------------- xg GEMM (layer 1): 256x256 8-wave pipelined -------------
// R17: T3+T4 port. 512 thr (8 waves 2Mx4N), BK=64, 128 KB LDS dbuf over
// K-tiles. During kt's 4 quadrant-phases, waves stage kt+1's 4 half-tiles
// (16 KB each, 2 gload_lds/thread) into the opposite buffer. At each K-tile
// boundary: issue next half FIRST, then vmcnt(2) (never 0) + raw s_barrier
// -- each wave drains its OWN kt loads; collectively kt is resident.
// NO __syncthreads in the loop (it emits vmcnt(0) and kills the pipeline).
// Per-phase: 12 ds_read_b128 -> setprio(1) 16 MFMA setprio(0) -> s_barrier
// (keeps skew <1 phase so dbuf reuse is safe; compiler's own lgkmcnt
// ordering covers ds_read->MFMA).
__global__ __launch_bounds__(512, 1) void xg_gemm(
    const u16* __restrict__ X, int Kx, int Kfull, const u16* __restrict__ Wc,
    const float* __restrict__ bsumL, u16* __restrict__ xg) {
  __shared__ __align__(16) char lds[131072];  // 2 x [A 32K | B 32K]
  const int tid = threadIdx.x;
  const int lane = tid & 63, wv = tid >> 6;
  const int wm = wv >> 2, wn = wv & 3;
  const int col = lane & 15, quad = lane >> 4;
  // supertile swizzle: 4bx x 4by contiguous for L2 reuse
  const int w = blockIdx.x & 15, s = blockIdx.x >> 4;
  const int bx = (s % 20) * 4 + (w & 3);   // [0,80) M-tiles
  const int by = (s / 20) * 4 + (w >> 2);  // [0,16) N-tiles
  const int tb0 = bx * 256;
  const int d = by >> 3;

  f32x4 zero = {0.f, 0.f, 0.f, 0.f};
  f32x4 acc[8][4];
#pragma unroll
  for (int i = 0; i < 8; ++i)
#pragma unroll
    for (int j = 0; j < 4; ++j) acc[i][j] = zero;

  const int nkt = Kx >> 6;  // 16

  // stage half j (0=A0,1=A1,2=B0,3=B1) of K-tile kt into buf[kt&1]
  auto stage = [&](int kt, int j) {
    char* dst = lds + (kt & 1) * 65536 + ((j >> 1) * 32768) + ((j & 1) * 16384);
#pragma unroll
    for (int i = 0; i < 2; ++i) {
      int idx = i * 512 + tid;  // [0,1024)
      int row = idx >> 3, sl = idx & 7;
      int rr = (j & 1) * 128 + row;  // [0,256)
      int kk = kt * 64 + ((sl * 8) ^ ((rr & 7) << 3));
      const u16* gsrc;
      if (j < 2) {
        gsrc = X + (long)(tb0 + rr) * Kx + kk;
      } else {
        int n2 = (by & 7) * 256 + rr;  // packed col in [0,2048)
        int grow = ((n2 & 127) >> 5) * 512 + (n2 >> 7) * 32 + (n2 & 31);
        gsrc = Wc + ((long)d * G4 + grow) * Kfull + kk;
      }
      __builtin_amdgcn_global_load_lds(
          (const __attribute__((address_space(1))) void*)(const void*)gsrc,
          (__attribute__((address_space(3))) void*)(dst + i * 8192 + wv * 1024),
          16, 0, 0);
    }
  };

  // prologue: K-tile 0's 4 halves
#pragma unroll
  for (int j = 0; j < 4; ++j) stage(0, j);

#pragma unroll 1
  for (int kt = 0; kt < 16; ++kt) {
    // ---- boundary: kt resident; keep >=1 half in flight ----
    if (kt + 1 < 16) {
      stage(kt + 1, 0);
      asm volatile("s_waitcnt vmcnt(2)" ::: "memory");
    } else {
      asm volatile("s_waitcnt vmcnt(0)" ::: "memory");
    }
    __builtin_amdgcn_sched_barrier(0);
    __builtin_amdgcn_s_barrier();
    __builtin_amdgcn_sched_barrier(0);

    const u16* As = (const u16*)(lds + (kt & 1) * 65536);
    const u16* Bs = As + 16384;

#pragma unroll
    for (int q = 0; q < 4; ++q) {
      const int qr = q >> 1, qc = q & 1;
      short8 afr[4][2], bfr[2][2];
#pragma unroll
      for (int mf = 0; mf < 4; ++mf) {
        int rm = wm * 128 + qr * 64 + mf * 16 + col;
#pragma unroll
        for (int ks = 0; ks < 2; ++ks) {
          int ksub = ks * 32 + quad * 8;
          afr[mf][ks] =
              *(const short8*)(As + rm * 64 + (ksub ^ ((rm & 7) << 3)));
        }
      }
#pragma unroll
      for (int nf = 0; nf < 2; ++nf) {
        int bn = wn * 64 + qc * 32 + nf * 16 + col;
#pragma unroll
        for (int ks = 0; ks < 2; ++ks) {
          int ksub = ks * 32 + quad * 8;
          bfr[nf][ks] =
              *(const short8*)(Bs + bn * 64 + (ksub ^ ((bn & 7) << 3)));
        }
      }
      if (q > 0 && kt + 1 < 16) stage(kt + 1, q);
      __builtin_amdgcn_s_setprio(1);
#pragma unroll
      for (int mf = 0; mf < 4; ++mf)
#pragma unroll
        for (int nf = 0; nf < 2; ++nf)
#pragma unroll
          for (int ks = 0; ks < 2; ++ks)
            acc[qr * 4 + mf][qc * 2 + nf] =
                __builtin_amdgcn_mfma_f32_16x16x32_bf16(
                    afr[mf][ks], bfr[nf][ks], acc[qr * 4 + mf][qc * 2 + nf], 0,
                    0, 0);
      __builtin_amdgcn_s_setprio(0);
      __builtin_amdgcn_sched_barrier(0);
      __builtin_amdgcn_s_barrier();
      __builtin_amdgcn_sched_barrier(0);
    }
  }

  // ---- epilogue: bias + store (same xg layout as before) ----
#pragma unroll
  for (int nf = 0; nf < 4; ++nf) {
    int nc = wn * 64 + nf * 16 + col;
    int n2 = (by & 7) * 256 + nc;
    int colb = n2 >> 7, nq = n2 & 127;
    int g = nq >> 5, jn = nq & 31;
    float bias = bsumL[d * G4 + g * 512 + colb * 32 + jn];
#pragma unroll
    for (int mf = 0; mf < 8; ++mf) {
#pragma unroll
      for (int r = 0; r < 4; ++r) {
        int m = wm * 128 + mf * 16 + quad * 4 + r;
        int tb = tb0 + m, t = tb >> 9, b = tb & 511;
        long oi =
            ((((long)t * 2 + d) * 16 + colb) * 512 + b) * 128 + jn * 4 + g;
        xg[oi] = f2bf(acc[mf][nf][r] + bias);
      }
    }
  }
}

// ---------------- persistent bidirectional LSTM recurrence ----------------
// R16 structure (verified): Whh k<128 in registers, k in [128,512) in 96 KB
// LDS; ONE 64 KB full-h stage per step (one exposed LLC wait); per-writer
// flag slots; deferred HBM stores.
__global__ __launch_bounds__(256, 1) void lstm_pers(
    const u16* __restrict__ xg, const int* __restrict__ qv,
    const u16* __restrict__ Wc, int Kfull, int Kx, u16* __restrict__ hbuf,
    u16* __restrict__ h0cat, void* __restrict__ outp,
    const int* __restrict__ qlen, const int* __restrict__ flag,
    unsigned int* bar, int layer) {
  __shared__ __align__(16) char lds[163840];  // [Whh 96K][h-stage 64K]
  const int tid = threadIdx.x;
  const int lane = tid & 63, wv = tid >> 6;
  const int wm = wv & 1, wn = wv >> 1;
  const int col = lane & 15, quad = lane >> 4;
  const int l = blockIdx.x;
  const int colid = l & 31, mi = l >> 5;
  const int colb = colid & 15, j0 = colb * 32, d = colid >> 4;
  const int m0 = mi * 64;
  const int gid = l >> 4;  // == mi*2 + d (16 groups of 16 blocks)

  // ---- preload Whh k in [128,512) into LDS: [cc 6][row 128][64k swz] ----
#pragma unroll
  for (int p = 0; p < 24; ++p) {
    int c = p * 256 + tid;  // [0,6144)
    int cc = c >> 10, row = (c >> 3) & 127, sl = c & 7;
    int grow = (row >> 5) * 512 + j0 + (row & 31);
    int gk = Kx + 128 + cc * 64 + ((sl * 8) ^ ((row & 7) << 3));
    const u16* gsrc = Wc + ((long)d * G4 + grow) * Kfull + gk;
    __builtin_amdgcn_global_load_lds(
        (const __attribute__((address_space(1))) void*)(const void*)gsrc,
        (__attribute__((address_space(3))) void*)(lds + p * 4096 + wv * 1024),
        16, 0, 0);
  }
  const u16* WhhB = (const u16*)lds;  // u16 offset: cc*8192 + row*64 + kslot
  char* hstg = lds + 98304;           // 64 KB full-h stage [64 rows][512 k swz]
  u16* hLDS = (u16*)hstg;             // epilogue pack [64 m][32 jn] aliases

  // ---- Whh k in [0,128) as per-lane B-fragments: breg[g][chunk] ----
  short8 breg[4][4];
#pragma unroll
  for (int g = 0; g < 4; ++g) {
    int grow = g * 512 + j0 + wn * 16 + col;
    const u16* wp = Wc + ((long)d * G4 + grow) * Kfull + Kx;
#pragma unroll
    for (int c4 = 0; c4 < 4; ++c4)
      breg[g][c4] = *(const short8*)(wp + c4 * 32 + quad * 8);
  }

  float creg[2][4];
#pragma unroll
  for (int i = 0; i < 2; ++i)
#pragma unroll
    for (int r = 0; r < 4; ++r) creg[i][r] = 0.f;
  const int isbf = *flag;
  f32x4 zero = {0.f, 0.f, 0.f, 0.f};

  __syncthreads();  // Whh resident

#pragma unroll 1
  for (int t = 0; t < NW; ++t) {
    const int tq = d ? (NW - 1 - t) : t;

    // x-gate prefetch (issued before the poll)
    ushort4 xgv[2][4];
    if (layer == 0) {
#pragma unroll
      for (int mf = 0; mf < 2; ++mf)
#pragma unroll
        for (int r = 0; r < 4; ++r) {
          int m = wm * 32 + mf * 16 + quad * 4 + r;
          int q = qv[(m0 + m) * NW + tq];
          xgv[mf][r] = *(const ushort4*)(xg + (long)q * 4096 +
                                         ((d * 16 + colb) << 7) +
                                         (wn * 16 + col) * 4);
        }
    } else {
      const u16* xgt =
          xg + ((((long)tq * 2 + d) * 16 + colb) * 512 + m0) * 128;
#pragma unroll
      for (int mf = 0; mf < 2; ++mf)
#pragma unroll
        for (int r = 0; r < 4; ++r) {
          int m = wm * 32 + mf * 16 + quad * 4 + r;
          xgv[mf][r] = *(const ushort4*)(xgt + m * 128 + (wn * 16 + col) * 4);
        }
    }

    f32x4 acc[2][4];  // [mf][gate]
#pragma unroll
    for (int i = 0; i < 2; ++i)
#pragma unroll
      for (int j = 0; j < 4; ++j) acc[i][j] = zero;

    if (t > 0) {
      // ---- per-writer slot poll: all 16 writers of (mi,d) signaled t ----
      if (wv == 0) {
        u32* sp = bar + gid * 16 + (lane & 15);
        while (__ballot((int)(__hip_atomic_load(sp, __ATOMIC_RELAXED,
                                                __HIP_MEMORY_SCOPE_AGENT) <
                              (u32)t)))
          __builtin_amdgcn_s_sleep(1);
      }
      __syncthreads();

      const u16* hp =
          hbuf + ((t - 1) & 1) * (2L * NB * NH) + ((long)d * NB + m0) * NH;
      // ---- stage the FULL 64 rows x 512 k = 64 KB in one shot, SC1 ----
#pragma unroll
      for (int p = 0; p < 16; ++p) {
        int c = p * 256 + tid;  // [0,4096)
        int row = c >> 6, slot = c & 63;
        int kk = (slot >> 3) * 64 + (((slot & 7) * 8) ^ ((row & 7) << 3));
        const u16* gsrc = hp + (long)row * NH + kk;
        __builtin_amdgcn_global_load_lds(
            (const __attribute__((address_space(1))) void*)(const void*)gsrc,
            (__attribute__((address_space(3))) void*)(hstg + p * 4096 +
                                                      wv * 1024),
            16, 0, 16 /* SC1: agent-coherent read from LLC */);
      }
      __syncthreads();  // all h resident (the ONE exposed LLC wait)

      const u16* As = (const u16*)hstg;
#pragma unroll
      for (int ks = 0; ks < 16; ++ks) {
        const int ksub = ks * 32 + quad * 8;  // [0,512)
        short8 afr[2];
#pragma unroll
        for (int mf = 0; mf < 2; ++mf) {
          int rm = wm * 32 + mf * 16 + col;
          afr[mf] = *(const short8*)(As + rm * 512 + (ksub & ~63) +
                                     ((ksub & 63) ^ ((rm & 7) << 3)));
        }
#pragma unroll
        for (int g = 0; g < 4; ++g) {
          short8 bfr;
          if (ks < 4) {
            bfr = breg[g][ks];  // k < 128 from registers
          } else {
            int br = g * 32 + wn * 16 + col;
            int kp = ksub - 128;  // [0,384)
            bfr = *(const short8*)(WhhB + (kp >> 6) * 8192 + br * 64 +
                                   ((kp & 63) ^ ((br & 7) << 3)));
          }
#pragma unroll
          for (int mf = 0; mf < 2; ++mf)
            acc[mf][g] = __builtin_amdgcn_mfma_f32_16x16x32_bf16(
                afr[mf], bfr, acc[mf][g], 0, 0, 0);
        }
      }
      __syncthreads();  // all A-reads done -> pack (aliases hstg) safe
    }

    // ---- register-only cell update; pack h into 4 KB LDS ----
#pragma unroll
    for (int mf = 0; mf < 2; ++mf)
#pragma unroll
      for (int r = 0; r < 4; ++r) {
        int m = wm * 32 + mf * 16 + quad * 4 + r;
        const u16* xv = (const u16*)&xgv[mf][r];
        float gi = acc[mf][0][r] + bf2f(xv[0]);
        float gf = acc[mf][1][r] + bf2f(xv[1]);
        float gg = acc[mf][2][r] + bf2f(xv[2]);
        float go = acc[mf][3][r] + bf2f(xv[3]);
        float si = sigm(gi);
        float sf = sigm(gf);
        float so = sigm(go);
        float cn = sf * creg[mf][r] + si * fast_tanh(gg);
        float h = so * fast_tanh(cn);
        creg[mf][r] = cn;
        hLDS[m * 32 + wn * 16 + col] = f2bf(h);
        // fp32 output path: store full-precision h directly (rare rows)
        if (layer == 1 && !isbf) {
          int bg = m0 + m;
          if (qlen[bg] - 1 == tq)
            ((float*)outp)[(long)bg * (2 * NH) + d * NH + j0 + wn * 16 + col] =
                h;
        }
      }
    __syncthreads();

    // ---- hbuf (LLC) stores; keep values in regs for deferred HBM stores --
    u16* hnxt = hbuf + (t & 1) * (2L * NB * NH);
    u32 hw[4];
    int bgp[4], jgp[4];
#pragma unroll
    for (int p = 0; p < 4; ++p) {
      int c = p * 256 + tid;  // [0,1024) pairs
      int m = c >> 4, pr = c & 15;
      hw[p] = ((const u32*)hLDS)[m * 16 + pr];
      bgp[p] = m0 + m;
      jgp[p] = j0 + pr * 2;
      __hip_atomic_store(
          (u32*)(hnxt + ((long)d * NB + bgp[p]) * NH + jgp[p]), hw[p],
          __ATOMIC_RELAXED, __HIP_MEMORY_SCOPE_AGENT);
    }

    // ---- drain hbuf stores, then signal own slot (non-blocking) ----
    if (t < NW - 1) {
      __syncthreads();  // drains vmcnt: hbuf stores visible at LLC
      if (tid == 0)
        __hip_atomic_store(bar + gid * 16 + colb, (u32)(t + 1),
                           __ATOMIC_RELAXED, __HIP_MEMORY_SCOPE_AGENT);
    }

    // ---- deferred HBM stores (off the rendezvous drain path) ----
#pragma unroll
    for (int p = 0; p < 4; ++p) {
      if (layer == 0) {
        *(u32*)(h0cat + ((long)tq * NB + bgp[p]) * (2 * NH) + d * NH +
                jgp[p]) = hw[p];
      } else if (isbf && qlen[bgp[p]] - 1 == tq) {
        *(u32*)((u16*)outp + (long)bgp[p] * (2 * NH) + d * NH + jgp[p]) =
            hw[p];
      }
    }
  }
}

extern "C" void kernel_launch(void* const* d_in, const int* in_sizes, int n_in,
                              void* d_out, int out_size, void* d_ws,
                              size_t ws_size, hipStream_t stream) {
  const int* qv = (const int*)d_in[0];
  const int* ql = (const int*)d_in[1];
  const void* lookup = d_in[2];
  const void* wih0 = d_in[3];
  const void* whh0 = d_in[4];
  const void* b0 = d_in[5];
  const void* wih1 = d_in[6];
  const void* whh1 = d_in[7];
  const void* b1 = d_in[8];

  char* ws = (char*)d_ws;
  size_t off = 0;
  int* flag = (int*)ws;                 off += 256;
  unsigned int* bar = (unsigned int*)(ws + off); off += 8192;
  float* bsum = (float*)(ws + off);     off += 2L * 2 * G4 * 4;        // 32 KB
  u16* Wc0 = (u16*)(ws + off);          off += 2L * G4 * 1024 * 2;     // 8 MB
  u16* Wc1 = (u16*)(ws + off);          off += 2L * G4 * 1536 * 2;     // 12 MB
  u16* hbuf = (u16*)(ws + off);         off += 2L * 2 * NB * NH * 2;   // 2 MB
  u16* h0cat = (u16*)(ws + off);        off += (size_t)NW * NB * 2 * NH * 2; // 40 MB
  u16* xg = (u16*)(ws + off);           off += (size_t)NW * 2 * 16 * 512 * 128 * 2; // 168 MB
  u16* tableT = h0cat;  // tableT (12.3 MB) aliases h0cat: dead before layer0
  u16* G = xg;  // G (98.3 MB) aliases xg: dead once layer-1 xg_gemm writes

  detect_kernel<<<1, 64, 0, stream>>>((const u16*)lookup, flag);
  table_kernel<<<dim3(188, 8), dim3(64, 4), 0, stream>>>(lookup, flag, tableT);
  {
    long total = 2L * G4 * 1024 + 2L * G4 * 1536 + 2L * 2 * G4 + 4096 + 512;
    int blocks = (int)((total + 255) / 256);
    pack_kernel<<<blocks, 256, 0, stream>>>(wih0, whh0, b0, wih1, whh1, b1,
                                            flag, Wc0, Wc1, bsum, G, bar);
  }

  // layer 0: per-vocab gate GEMM + fused recurrence gather
  g_gemm<<<94 * 32, 256, 0, stream>>>(tableT, Wc0, bsum, G);
  lstm_pers<<<256, 256, 0, stream>>>(G, qv, Wc0, 1024, 512, hbuf, h0cat,
                                     d_out, ql, flag, bar, 0);
  // layer 1: 256^2 8-wave pipelined GEMM
  xg_gemm<<<1280, 512, 0, stream>>>(h0cat, 1024, 1536, Wc1, bsum + 2 * G4, xg);
  lstm_pers<<<256, 256, 0, stream>>>(xg, qv, Wc1, 1536, 1024, hbuf, h0cat,
                                     d_out, ql, flag, bar + 256, 1);
}

// Round 10
// 846.849 us; speedup vs baseline: 1.0869x; 1.0869x over previous
//
#include <hip/hip_runtime.h>
#include <hip/hip_bf16.h>
#include <stdint.h>

#define NB 512
#define NW 40
#define NE 512
#define NH 512
#define NV 12000
#define G4 2048

typedef unsigned short u16;
typedef unsigned int u32;
typedef unsigned long long u64;
typedef __attribute__((ext_vector_type(8))) short short8;
typedef __attribute__((ext_vector_type(4))) float f32x4;

__device__ __forceinline__ unsigned short f2bf(float f) {
  unsigned int u = __float_as_uint(f);
  u += 0x7FFF + ((u >> 16) & 1);
  return (unsigned short)(u >> 16);
}
__device__ __forceinline__ float bf2f(unsigned short b) {
  return __uint_as_float(((unsigned int)b) << 16);
}
__device__ __forceinline__ float loadIn(const void* p, long i, int bf) {
  return bf ? bf2f(((const u16*)p)[i]) : ((const float*)p)[i];
}
// exp-based tanh: |err| ~1e-7 abs, saturates cleanly (exp->inf => 1).
__device__ __forceinline__ float fast_tanh(float x) {
  float ax = __builtin_fabsf(x);
  float t = 1.f - 2.f * __builtin_amdgcn_rcpf(__expf(ax + ax) + 1.f);
  return __builtin_copysignf(t, x);
}
__device__ __forceinline__ float sigm(float x) {
  return __builtin_amdgcn_rcpf(1.f + __expf(-x));
}

// ---------------- dtype detector ----------------
__global__ void detect_kernel(const u16* p, int* flag) {
  __shared__ int cnt;
  int i = threadIdx.x;
  if (i == 0) cnt = 0;
  __syncthreads();
  unsigned short u = p[2 * (i * 1001)];
  int e = (u >> 7) & 0xFF;
  if (e >= 100 && e <= 126) atomicAdd(&cnt, 1);
  __syncthreads();
  if (i == 0) *flag = (cnt >= 32) ? 1 : 0;
}

// ---------------- tableT = bf16(tanh(lookup_W^T)), (V, E) ----------------
// R18: fast_tanh (err 1e-7 << bf16 ulp; tableT only feeds g_gemm via bf16).
__global__ void table_kernel(const void* lookup, const int* flag, u16* tableT) {
  __shared__ float tile[64][65];
  int bf = *flag;
  int v0 = blockIdx.x * 64, e0 = blockIdx.y * 64;
  int tx = threadIdx.x, ty = threadIdx.y;  // (64,4)
#pragma unroll
  for (int r = 0; r < 16; ++r) {
    int e = r * 4 + ty, v = tx;
    if (v0 + v < NV)
      tile[e][v] = fast_tanh(loadIn(lookup, (long)(e0 + e) * NV + v0 + v, bf));
  }
  __syncthreads();
#pragma unroll
  for (int r = 0; r < 16; ++r) {
    int v = r * 4 + ty, e = tx;
    if (v0 + v < NV)
      tableT[(long)(v0 + v) * NE + e0 + e] = f2bf(tile[e][v]);
  }
}

// ---------------- pack weights: Wc[d] rows = [wih | whh], bf16 ------------
// Also writes G[0] = bias row (layer0) and zeroes the 512-slot bar region
// (layer0 uses bar[0..255], layer1 bar[256..511] -- no zero_bar dispatches).
__global__ void pack_kernel(const void* wih0, const void* whh0, const void* b0,
                            const void* wih1, const void* whh1, const void* b1,
                            const int* flag, u16* Wc0, u16* Wc1, float* bsum,
                            u16* G, unsigned int* bar) {
  const long N0 = 2L * G4 * 1024, N1 = 2L * G4 * 1536;
  const long NB2 = 2L * 2 * G4;
  long idx = (long)blockIdx.x * 256 + threadIdx.x;
  int bf = *flag;
  if (idx < N0) {
    int d = (int)(idx / (G4 * 1024));
    int rem = (int)(idx % (long)(G4 * 1024));
    int g = rem / 1024, k = rem % 1024;
    float v = (k < 512) ? loadIn(wih0, ((long)d * G4 + g) * 512 + k, bf)
                        : loadIn(whh0, ((long)d * G4 + g) * 512 + (k - 512), bf);
    Wc0[idx] = f2bf(v);
  } else if (idx < N0 + N1) {
    long i2 = idx - N0;
    int d = (int)(i2 / (G4 * 1536));
    int rem = (int)(i2 % (long)(G4 * 1536));
    int g = rem / 1536, k = rem % 1536;
    float v = (k < 1024) ? loadIn(wih1, ((long)d * G4 + g) * 1024 + k, bf)
                         : loadIn(whh1, ((long)d * G4 + g) * 512 + (k - 1024), bf);
    Wc1[i2] = f2bf(v);
  } else if (idx < N0 + N1 + NB2) {
    long i3 = idx - N0 - N1;  // [layer][d][g]
    int layer = (int)(i3 / (2 * G4));
    int d = (int)((i3 / G4) & 1);
    int g = (int)(i3 % G4);
    const void* bb = layer ? b1 : b0;
    float v = loadIn(bb, (long)d * 2 * G4 + g, bf) +
              loadIn(bb, (long)d * 2 * G4 + G4 + g, bf);
    bsum[i3] = v;
  } else if (idx < N0 + N1 + NB2 + 4096) {
    int n = (int)(idx - N0 - N1 - NB2);  // [0,4096): G[0] bias row
    int d = n >> 11, loc = n & 2047;
    int colb = loc >> 7, rr = loc & 127;
    int jn = rr >> 2, g = rr & 3;
    int grow = g * 512 + colb * 32 + jn;
    float v = loadIn(b0, (long)d * 2 * G4 + grow, bf) +
              loadIn(b0, (long)d * 2 * G4 + G4 + grow, bf);
    G[n] = f2bf(v);
  } else if (idx < N0 + N1 + NB2 + 4096 + 512) {
    bar[(int)(idx - N0 - N1 - NB2 - 4096)] = 0u;
  }
}

// ---------------- G GEMM: G[1+v] = tableT[v] @ Wih0^T + bias --------------
// layer-0 x-gates depend on the token only through q (12001 distinct
// values) -- compute per-VOCAB-ROW gates once (50 GF) instead of per-token.
// G row layout: [d 2][colb 16][jn*4+g 128] (matches lstm xgv gather).
__global__ __launch_bounds__(256, 3) void g_gemm(
    const u16* __restrict__ tableT, const u16* __restrict__ Wc,
    const float* __restrict__ bsumL, u16* __restrict__ G) {
  __shared__ __align__(16) char lds[32768];  // A 16K + B 16K
  const int tid = threadIdx.x;
  const int lane = tid & 63, wv = tid >> 6;
  const int wm = wv & 1, wn = wv >> 1;
  const int col = lane & 15, quad = lane >> 4;
  const int bx = blockIdx.x >> 5;  // 0..93
  const int by = blockIdx.x & 31;
  const int tb0 = bx * 128;  // vocab row base
  const int d = by >> 4, colb = by & 15, j0 = colb * 32;

  f32x4 zero = {0.f, 0.f, 0.f, 0.f};
  f32x4 acc[4][4];
#pragma unroll
  for (int i = 0; i < 4; ++i)
#pragma unroll
    for (int j = 0; j < 4; ++j) acc[i][j] = zero;

  for (int it = 0; it < 8; ++it) {
    int k0 = it << 6;
#pragma unroll
    for (int p = 0; p < 8; ++p) {
      int c = p * 256 + tid;  // [0,2048)
      const u16* gsrc;
      if (c < 1024) {  // A rows (vocab)
        int r = c >> 3, sl = c & 7;
        int kk = k0 + ((sl * 8) ^ ((r & 7) << 3));
        gsrc = tableT + (long)(tb0 + r) * 512 + kk;
      } else {
        int cb = c - 1024;
        int r = cb >> 3, sl = cb & 7;
        int kk = k0 + ((sl * 8) ^ ((r & 7) << 3));
        int grow = (r >> 5) * 512 + j0 + (r & 31);
        gsrc = Wc + ((long)d * G4 + grow) * 1024 + kk;  // wih part (k<512)
      }
      __builtin_amdgcn_global_load_lds(
          (const __attribute__((address_space(1))) void*)(const void*)gsrc,
          (__attribute__((address_space(3))) void*)(lds + p * 4096 + wv * 1024),
          16, 0, 0);
    }
    __syncthreads();
    const u16* As = (const u16*)lds;
    const u16* Bs = (const u16*)(lds + 16384);
#pragma unroll
    for (int ks = 0; ks < 2; ++ks) {
      short8 afr[4], bfr[4];
#pragma unroll
      for (int mf = 0; mf < 4; ++mf) {
        int rm = wm * 64 + mf * 16 + col;
        int sl = (ks * 32 + quad * 8) ^ ((rm & 7) << 3);
        afr[mf] = *(const short8*)(As + rm * 64 + sl);
      }
#pragma unroll
      for (int nf = 0; nf < 4; ++nf) {
        int br = wn * 64 + nf * 16 + col;
        int sl = (ks * 32 + quad * 8) ^ ((br & 7) << 3);
        bfr[nf] = *(const short8*)(Bs + br * 64 + sl);
      }
#pragma unroll
      for (int mf = 0; mf < 4; ++mf)
#pragma unroll
        for (int nf = 0; nf < 4; ++nf)
          acc[mf][nf] = __builtin_amdgcn_mfma_f32_16x16x32_bf16(
              afr[mf], bfr[nf], acc[mf][nf], 0, 0, 0);
    }
    __syncthreads();
  }

  float bias[4];
#pragma unroll
  for (int nf = 0; nf < 4; ++nf) {
    int n = wn * 64 + nf * 16 + col;
    bias[nf] = bsumL[d * G4 + (n >> 5) * 512 + j0 + (n & 31)];
  }
#pragma unroll
  for (int mf = 0; mf < 4; ++mf)
#pragma unroll
    for (int nf = 0; nf < 4; ++nf) {
      int n = wn * 64 + nf * 16 + col;
      int g = n >> 5, jn = n & 31;
#pragma unroll
      for (int r = 0; r < 4; ++r) {
        int m = wm * 64 + mf * 16 + quad * 4 + r;
        int v = tb0 + m;
        if (v < NV)
          G[(long)(v + 1) * 4096 + ((d * 16 + colb) << 7) + jn * 4 + g] =
              f2bf(acc[mf][nf][r] + bias[nf]);
      }
    }
}

// ---------------- xg GEMM (layer 1): xg[t][d][col][b][jn*4+g] -------------
// R18: reverted to the verified R16 m97 form (128x128, BK=64, 4 waves,
// supertile swizzle). R17's 8-phase 256^2 port measured SLOWER (257us,
// 668 TF vs ~210us/900 TF) -- falsifier triggered, m97 declared the
// structure ceiling for this GEMM in this harness.
__global__ __launch_bounds__(256, 3) void xg_gemm(
    const u16* __restrict__ X, int Kx, int Kfull, const u16* __restrict__ Wc,
    const float* __restrict__ bsumL, u16* __restrict__ xg) {
  __shared__ __align__(16) char lds[32768];  // A 16K + B 16K
  const int tid = threadIdx.x;
  const int lane = tid & 63, wv = tid >> 6;
  const int wm = wv & 1, wn = wv >> 1;
  const int col = lane & 15, quad = lane >> 4;
  const int s = blockIdx.x >> 5, w = blockIdx.x & 31;
  const int bx = (s % 40) * 4 + (w & 3);
  const int by = (s / 40) * 8 + (w >> 2);
  const int tb0 = bx * 128;
  const int d = by >> 4, colb = by & 15, j0 = colb * 32;

  f32x4 zero = {0.f, 0.f, 0.f, 0.f};
  f32x4 acc[4][4];
#pragma unroll
  for (int i = 0; i < 4; ++i)
#pragma unroll
    for (int j = 0; j < 4; ++j) acc[i][j] = zero;

  const int iters = Kx >> 6;
  for (int it = 0; it < iters; ++it) {
    int k0 = it << 6;
#pragma unroll
    for (int p = 0; p < 8; ++p) {
      int c = p * 256 + tid;  // [0,2048)
      const u16* gsrc;
      if (c < 1024) {  // A rows 0..127
        int r = c >> 3, sl = c & 7;
        int kk = k0 + ((sl * 8) ^ ((r & 7) << 3));
        gsrc = X + (long)(tb0 + r) * Kx + kk;
      } else {
        int cb = c - 1024;
        int r = cb >> 3, sl = cb & 7;
        int kk = k0 + ((sl * 8) ^ ((r & 7) << 3));
        int grow = (r >> 5) * 512 + j0 + (r & 31);
        gsrc = Wc + ((long)d * G4 + grow) * Kfull + kk;
      }
      __builtin_amdgcn_global_load_lds(
          (const __attribute__((address_space(1))) void*)(const void*)gsrc,
          (__attribute__((address_space(3))) void*)(lds + p * 4096 + wv * 1024),
          16, 0, 0);
    }
    __syncthreads();
    const u16* As = (const u16*)lds;
    const u16* Bs = (const u16*)(lds + 16384);
#pragma unroll
    for (int ks = 0; ks < 2; ++ks) {
      short8 afr[4], bfr[4];
#pragma unroll
      for (int mf = 0; mf < 4; ++mf) {
        int rm = wm * 64 + mf * 16 + col;
        int sl = (ks * 32 + quad * 8) ^ ((rm & 7) << 3);
        afr[mf] = *(const short8*)(As + rm * 64 + sl);
      }
#pragma unroll
      for (int nf = 0; nf < 4; ++nf) {
        int br = wn * 64 + nf * 16 + col;
        int sl = (ks * 32 + quad * 8) ^ ((br & 7) << 3);
        bfr[nf] = *(const short8*)(Bs + br * 64 + sl);
      }
#pragma unroll
      for (int mf = 0; mf < 4; ++mf)
#pragma unroll
        for (int nf = 0; nf < 4; ++nf)
          acc[mf][nf] = __builtin_amdgcn_mfma_f32_16x16x32_bf16(
              afr[mf], bfr[nf], acc[mf][nf], 0, 0, 0);
    }
    __syncthreads();
  }

  float bias[4];
#pragma unroll
  for (int nf = 0; nf < 4; ++nf) {
    int n = wn * 64 + nf * 16 + col;
    bias[nf] = bsumL[d * G4 + (n >> 5) * 512 + j0 + (n & 31)];
  }
#pragma unroll
  for (int mf = 0; mf < 4; ++mf)
#pragma unroll
    for (int nf = 0; nf < 4; ++nf) {
      int n = wn * 64 + nf * 16 + col;
      int g = n >> 5, jn = n & 31;
#pragma unroll
      for (int r = 0; r < 4; ++r) {
        int m = wm * 64 + mf * 16 + quad * 4 + r;
        int tb = tb0 + m, t = tb >> 9, b = tb & 511;
        long oi = ((((long)t * 2 + d) * 16 + colb) * 512 + b) * 128 + jn * 4 + g;
        xg[oi] = f2bf(acc[mf][nf][r] + bias[nf]);
      }
    }
}

// ---------------- persistent bidirectional LSTM recurrence ----------------
// R18 = R16 + breg2 + all-wave poll.
//  * breg2: Whh k in [384,512) also moves to registers (64 more VGPR, free
//    at 1 wave/SIMD). Whh LDS shrinks to k in [128,384) = 64 KB; LDS total
//    128 KB. Halves B-side LDS reads (bank conflicts 5.8e6 -> ~3e6).
//  * all-wave poll: every wave polls the same 16 slots and proceeds to its
//    staging share when it passes (post-poll __syncthreads dropped; the
//    h-resident barrier still covers cross-wave stage completion; all waves
//    passed the prior drain-barrier before any wave can re-stage the
//    aliased buffer). 4 barriers/step (was 5).
// Everything else is R16's verified structure: ONE 64 KB full-h stage per
// step (one exposed LLC wait), per-writer flag slots, deferred HBM stores.
__global__ __launch_bounds__(256, 1) void lstm_pers(
    const u16* __restrict__ xg, const int* __restrict__ qv,
    const u16* __restrict__ Wc, int Kfull, int Kx, u16* __restrict__ hbuf,
    u16* __restrict__ h0cat, void* __restrict__ outp,
    const int* __restrict__ qlen, const int* __restrict__ flag,
    unsigned int* bar, int layer) {
  __shared__ __align__(16) char lds[131072];  // [Whh 64K][h-stage 64K]
  const int tid = threadIdx.x;
  const int lane = tid & 63, wv = tid >> 6;
  const int wm = wv & 1, wn = wv >> 1;
  const int col = lane & 15, quad = lane >> 4;
  const int l = blockIdx.x;
  const int colid = l & 31, mi = l >> 5;
  const int colb = colid & 15, j0 = colb * 32, d = colid >> 4;
  const int m0 = mi * 64;
  const int gid = l >> 4;  // == mi*2 + d (16 groups of 16 blocks)

  // ---- preload Whh k in [128,384) into LDS: [cc 4][row 128][64k swz] ----
#pragma unroll
  for (int p = 0; p < 16; ++p) {
    int c = p * 256 + tid;  // [0,4096)
    int cc = c >> 10, row = (c >> 3) & 127, sl = c & 7;
    int grow = (row >> 5) * 512 + j0 + (row & 31);
    int gk = Kx + 128 + cc * 64 + ((sl * 8) ^ ((row & 7) << 3));
    const u16* gsrc = Wc + ((long)d * G4 + grow) * Kfull + gk;
    __builtin_amdgcn_global_load_lds(
        (const __attribute__((address_space(1))) void*)(const void*)gsrc,
        (__attribute__((address_space(3))) void*)(lds + p * 4096 + wv * 1024),
        16, 0, 0);
  }
  const u16* WhhB = (const u16*)lds;  // u16 offset: cc*8192 + row*64 + kslot
  char* hstg = lds + 65536;           // 64 KB full-h stage [64 rows][512 k swz]
  u16* hLDS = (u16*)hstg;             // epilogue pack [64 m][32 jn] aliases

  // ---- Whh k in [0,128) and [384,512) as per-lane B-fragments ----
  short8 breg[4][4], breg2[4][4];
#pragma unroll
  for (int g = 0; g < 4; ++g) {
    int grow = g * 512 + j0 + wn * 16 + col;
    const u16* wp = Wc + ((long)d * G4 + grow) * Kfull + Kx;
#pragma unroll
    for (int c4 = 0; c4 < 4; ++c4) {
      breg[g][c4] = *(const short8*)(wp + c4 * 32 + quad * 8);
      breg2[g][c4] = *(const short8*)(wp + 384 + c4 * 32 + quad * 8);
    }
  }

  float creg[2][4];
#pragma unroll
  for (int i = 0; i < 2; ++i)
#pragma unroll
    for (int r = 0; r < 4; ++r) creg[i][r] = 0.f;
  const int isbf = *flag;
  f32x4 zero = {0.f, 0.f, 0.f, 0.f};

  __syncthreads();  // Whh resident

#pragma unroll 1
  for (int t = 0; t < NW; ++t) {
    const int tq = d ? (NW - 1 - t) : t;

    // x-gate prefetch (issued before the poll)
    ushort4 xgv[2][4];
    if (layer == 0) {
#pragma unroll
      for (int mf = 0; mf < 2; ++mf)
#pragma unroll
        for (int r = 0; r < 4; ++r) {
          int m = wm * 32 + mf * 16 + quad * 4 + r;
          int q = qv[(m0 + m) * NW + tq];
          xgv[mf][r] = *(const ushort4*)(xg + (long)q * 4096 +
                                         ((d * 16 + colb) << 7) +
                                         (wn * 16 + col) * 4);
        }
    } else {
      const u16* xgt =
          xg + ((((long)tq * 2 + d) * 16 + colb) * 512 + m0) * 128;
#pragma unroll
      for (int mf = 0; mf < 2; ++mf)
#pragma unroll
        for (int r = 0; r < 4; ++r) {
          int m = wm * 32 + mf * 16 + quad * 4 + r;
          xgv[mf][r] = *(const ushort4*)(xgt + m * 128 + (wn * 16 + col) * 4);
        }
    }

    f32x4 acc[2][4];  // [mf][gate]
#pragma unroll
    for (int i = 0; i < 2; ++i)
#pragma unroll
      for (int j = 0; j < 4; ++j) acc[i][j] = zero;

    if (t > 0) {
      // ---- all-wave poll: all 16 writers of (mi,d) signaled t ----
      {
        u32* sp = bar + gid * 16 + (lane & 15);
        while (__ballot((int)(__hip_atomic_load(sp, __ATOMIC_RELAXED,
                                                __HIP_MEMORY_SCOPE_AGENT) <
                              (u32)t)))
          __builtin_amdgcn_s_sleep(1);
      }

      const u16* hp =
          hbuf + ((t - 1) & 1) * (2L * NB * NH) + ((long)d * NB + m0) * NH;
      // ---- stage the FULL 64 rows x 512 k = 64 KB in one shot, SC1 ----
#pragma unroll
      for (int p = 0; p < 16; ++p) {
        int c = p * 256 + tid;  // [0,4096)
        int row = c >> 6, slot = c & 63;
        int kk = (slot >> 3) * 64 + (((slot & 7) * 8) ^ ((row & 7) << 3));
        const u16* gsrc = hp + (long)row * NH + kk;
        __builtin_amdgcn_global_load_lds(
            (const __attribute__((address_space(1))) void*)(const void*)gsrc,
            (__attribute__((address_space(3))) void*)(hstg + p * 4096 +
                                                      wv * 1024),
            16, 0, 16 /* SC1: agent-coherent read from LLC */);
      }
      __syncthreads();  // all h resident (the ONE exposed LLC wait)

      const u16* As = (const u16*)hstg;
#pragma unroll
      for (int ks = 0; ks < 16; ++ks) {
        const int ksub = ks * 32 + quad * 8;  // [0,512)
        short8 afr[2];
#pragma unroll
        for (int mf = 0; mf < 2; ++mf) {
          int rm = wm * 32 + mf * 16 + col;
          afr[mf] = *(const short8*)(As + rm * 512 + (ksub & ~63) +
                                     ((ksub & 63) ^ ((rm & 7) << 3)));
        }
#pragma unroll
        for (int g = 0; g < 4; ++g) {
          short8 bfr;
          if (ks < 4) {
            bfr = breg[g][ks];  // k < 128 from registers
          } else if (ks >= 12) {
            bfr = breg2[g][ks - 12];  // k >= 384 from registers
          } else {
            int br = g * 32 + wn * 16 + col;
            int kp = ksub - 128;  // [0,256)
            bfr = *(const short8*)(WhhB + (kp >> 6) * 8192 + br * 64 +
                                   ((kp & 63) ^ ((br & 7) << 3)));
          }
#pragma unroll
          for (int mf = 0; mf < 2; ++mf)
            acc[mf][g] = __builtin_amdgcn_mfma_f32_16x16x32_bf16(
                afr[mf], bfr, acc[mf][g], 0, 0, 0);
        }
      }
      __syncthreads();  // all A-reads done -> pack (aliases hstg) safe
    }

    // ---- register-only cell update; pack h into 4 KB LDS ----
#pragma unroll
    for (int mf = 0; mf < 2; ++mf)
#pragma unroll
      for (int r = 0; r < 4; ++r) {
        int m = wm * 32 + mf * 16 + quad * 4 + r;
        const u16* xv = (const u16*)&xgv[mf][r];
        float gi = acc[mf][0][r] + bf2f(xv[0]);
        float gf = acc[mf][1][r] + bf2f(xv[1]);
        float gg = acc[mf][2][r] + bf2f(xv[2]);
        float go = acc[mf][3][r] + bf2f(xv[3]);
        float si = sigm(gi);
        float sf = sigm(gf);
        float so = sigm(go);
        float cn = sf * creg[mf][r] + si * fast_tanh(gg);
        float h = so * fast_tanh(cn);
        creg[mf][r] = cn;
        hLDS[m * 32 + wn * 16 + col] = f2bf(h);
        // fp32 output path: store full-precision h directly (rare rows)
        if (layer == 1 && !isbf) {
          int bg = m0 + m;
          if (qlen[bg] - 1 == tq)
            ((float*)outp)[(long)bg * (2 * NH) + d * NH + j0 + wn * 16 + col] =
                h;
        }
      }
    __syncthreads();

    // ---- hbuf (LLC) stores; keep values in regs for deferred HBM stores --
    u16* hnxt = hbuf + (t & 1) * (2L * NB * NH);
    u32 hw[4];
    int bgp[4], jgp[4];
#pragma unroll
    for (int p = 0; p < 4; ++p) {
      int c = p * 256 + tid;  // [0,1024) pairs
      int m = c >> 4, pr = c & 15;
      hw[p] = ((const u32*)hLDS)[m * 16 + pr];
      bgp[p] = m0 + m;
      jgp[p] = j0 + pr * 2;
      __hip_atomic_store(
          (u32*)(hnxt + ((long)d * NB + bgp[p]) * NH + jgp[p]), hw[p],
          __ATOMIC_RELAXED, __HIP_MEMORY_SCOPE_AGENT);
    }

    // ---- drain hbuf stores, then signal own slot (non-blocking) ----
    if (t < NW - 1) {
      __syncthreads();  // drains vmcnt: hbuf stores visible at LLC
      if (tid == 0)
        __hip_atomic_store(bar + gid * 16 + colb, (u32)(t + 1),
                           __ATOMIC_RELAXED, __HIP_MEMORY_SCOPE_AGENT);
    }

    // ---- deferred HBM stores (off the rendezvous drain path) ----
#pragma unroll
    for (int p = 0; p < 4; ++p) {
      if (layer == 0) {
        *(u32*)(h0cat + ((long)tq * NB + bgp[p]) * (2 * NH) + d * NH +
                jgp[p]) = hw[p];
      } else if (isbf && qlen[bgp[p]] - 1 == tq) {
        *(u32*)((u16*)outp + (long)bgp[p] * (2 * NH) + d * NH + jgp[p]) =
            hw[p];
      }
    }
  }
}

extern "C" void kernel_launch(void* const* d_in, const int* in_sizes, int n_in,
                              void* d_out, int out_size, void* d_ws,
                              size_t ws_size, hipStream_t stream) {
  const int* qv = (const int*)d_in[0];
  const int* ql = (const int*)d_in[1];
  const void* lookup = d_in[2];
  const void* wih0 = d_in[3];
  const void* whh0 = d_in[4];
  const void* b0 = d_in[5];
  const void* wih1 = d_in[6];
  const void* whh1 = d_in[7];
  const void* b1 = d_in[8];

  char* ws = (char*)d_ws;
  size_t off = 0;
  int* flag = (int*)ws;                 off += 256;
  unsigned int* bar = (unsigned int*)(ws + off); off += 8192;
  float* bsum = (float*)(ws + off);     off += 2L * 2 * G4 * 4;        // 32 KB
  u16* Wc0 = (u16*)(ws + off);          off += 2L * G4 * 1024 * 2;     // 8 MB
  u16* Wc1 = (u16*)(ws + off);          off += 2L * G4 * 1536 * 2;     // 12 MB
  u16* hbuf = (u16*)(ws + off);         off += 2L * 2 * NB * NH * 2;   // 2 MB
  u16* h0cat = (u16*)(ws + off);        off += (size_t)NW * NB * 2 * NH * 2; // 40 MB
  u16* xg = (u16*)(ws + off);           off += (size_t)NW * 2 * 16 * 512 * 128 * 2; // 168 MB
  u16* tableT = h0cat;  // tableT (12.3 MB) aliases h0cat: dead before layer0
  u16* G = xg;  // G (98.3 MB) aliases xg: dead once layer-1 xg_gemm writes

  detect_kernel<<<1, 64, 0, stream>>>((const u16*)lookup, flag);
  table_kernel<<<dim3(188, 8), dim3(64, 4), 0, stream>>>(lookup, flag, tableT);
  {
    long total = 2L * G4 * 1024 + 2L * G4 * 1536 + 2L * 2 * G4 + 4096 + 512;
    int blocks = (int)((total + 255) / 256);
    pack_kernel<<<blocks, 256, 0, stream>>>(wih0, whh0, b0, wih1, whh1, b1,
                                            flag, Wc0, Wc1, bsum, G, bar);
  }

  // layer 0: per-vocab gate GEMM + fused recurrence gather
  g_gemm<<<94 * 32, 256, 0, stream>>>(tableT, Wc0, bsum, G);
  lstm_pers<<<256, 256, 0, stream>>>(G, qv, Wc0, 1024, 512, hbuf, h0cat,
                                     d_out, ql, flag, bar, 0);
  // layer 1: m97 128^2 GEMM (verified form)
  xg_gemm<<<5120, 256, 0, stream>>>(h0cat, 1024, 1536, Wc1, bsum + 2 * G4, xg);
  lstm_pers<<<256, 256, 0, stream>>>(xg, qv, Wc1, 1536, 1024, hbuf, h0cat,
                                     d_out, ql, flag, bar + 256, 1);
}